// Round 30
// baseline (42.998 us; speedup 1.0000x reference)
//
#include <hip/hip_runtime.h>
#include <math.h>

// Problem constants
#define NB 2
#define NC 19      // classes
#define NH 128
#define NW 128
#define NCF 64     // feature channels
#define NHE 64     // ema logits H/W
#define NHX 32     // x_ema H/W
#define EPSC 1e-8f
#define NBLK 512   // pfst_main grid size

// d_ws: done counter @0 (4B, memset per launch) | part[NBLK*3] f32 @64
#define WS_PART_OFF 64

__device__ __forceinline__ int clampi(int v, int lo, int hi) {
    return v < lo ? lo : (v > hi ? hi : v);
}

// Single kernel (R29 champion + last-block final reduction).
// 4 lanes/pixel: lanes 0-1 pos / 2-3 neg (scan on -sims, IEEE-exact mirror);
// pair-split 25/24-tap selection scan; parallel 3-chunk in-block cell norms;
// T14 async-stage (ema regs->LDS deferred past phases 1-3).
__global__ __launch_bounds__(256) void pfst_main(
    const float* __restrict__ trg, const float* __restrict__ ema,
    const float* __restrict__ xe,  const float* __restrict__ mix,
    unsigned* __restrict__ done,   float* __restrict__ part,
    float* __restrict__ out)
{
    __shared__ float se[NC * 321];        // ema tile [19][8][40], stride 321 (pad)
    __shared__ float sx[NCF * 85];        // xe tile [64][4][21], stride 85 (pad)
    __shared__ float scn3[3 * 84];        // partial cell norms [3 chunks][84]
    __shared__ float red[4][3];
    __shared__ int lastflag;

    int tid = threadIdx.x;
    int l = tid & 3;                      // lane in quad
    int lc = l & 1;                       // scan-half / class-lane within pair
    bool posH = (l < 2);                  // pair role
    int q = tid >> 2;                     // pixel slot (0..63)
    int p0 = blockIdx.x * 64;
    int b = p0 >> 14;
    int h = (p0 >> 7) & 127;              // block-uniform
    int w0 = p0 & 127;                    // 0 or 64
    int w = w0 + q;

    int ey0 = (h - 7) >> 1, ex0 = (w0 - 7) >> 1;   // ema tile origin
    int by0 = (h - 6) >> 2, bx0 = (w0 - 6) >> 2;   // cell tile origin

    // ---------- Stage: xe->regs first, then ema->regs (issue order!) ----------
    float xreg[21];
    {
        const float* Xb = xe + b * (NCF * NHX * NHX);
        #pragma unroll
        for (int r = 0; r < 21; r++) {
            int idx = tid + r * 256;      // < 5376 always
            int ch = idx / 84; int rr = idx - ch * 84;
            int a = rr / 21;   int d = rr - a * 21;
            int gy = clampi(by0 + a, 0, 31), gx = clampi(bx0 + d, 0, 31);
            xreg[r] = Xb[ch * (NHX * NHX) + gy * 32 + gx];
        }
    }
    float ereg[24];
    {
        const float* Eb = ema + b * NC * (NHE * NHE);
        #pragma unroll
        for (int r = 0; r < 24; r++) {
            int idx = tid + r * 256;      // < 6144; valid < 6080
            if (idx < NC * 320) {
                int c = idx / 320; int rr = idx - c * 320;
                int rw = rr / 40;  int x = rr - rw * 40;
                int gy = clampi(ey0 + rw, 0, 63), gx = clampi(ex0 + x, 0, 63);
                ereg[r] = Eb[c * (NHE * NHE) + gy * 64 + gx];
            } else ereg[r] = 0.f;
        }
    }
    // Write xe to LDS (waits only on xe loads; ema loads stay in flight)
    #pragma unroll
    for (int r = 0; r < 21; r++) {
        int idx = tid + r * 256;
        int ch = idx / 84; int rr = idx - ch * 84;
        sx[ch * 85 + rr] = xreg[r];
    }
    __syncthreads();

    // ---------- In-block cell norms: 3-chunk parallel split ----------
    if (tid < 252) {
        int cell = tid % 84;
        int chunk = tid / 84;
        int ch0 = chunk * 21;
        int nch = (chunk == 2) ? 22 : 21;
        float s = 0.f;
        #pragma unroll
        for (int cc = 0; cc < 22; cc++) {
            if (cc < nch) {
                float v = sx[(ch0 + cc) * 85 + cell];
                s = fmaf(v, v, s);
            }
        }
        scn3[chunk * 84 + cell] = s;
    }
    __syncthreads();

    float mval = mix[(b << 14) + (h << 7) + w];
    bool active = mval < 0.5f;            // (1 - mix) > 0.5
    float lp = 0.f, ln = 0.f;
    float cm = (active && l == 0) ? 1.f : 0.f;

    float tx[10];
    float vsel[9]; int isel[9];

    if (active) {
        // ---------- Prefetch trg for this lane's 10 classes ----------
        const float* Tb = trg + b * NC * (NH * NW) + (h << 7) + w;
        #pragma unroll
        for (int jc = 0; jc < 10; jc++) {
            int c = lc + 2 * jc;
            tx[jc] = (c < NC) ? Tb[c * (NH * NW)] : 0.f;
        }

        // ---------- Phase 1: cell dots from LDS, 16 channels/lane ----------
        int bx = (w - 6) >> 2;
        int trow[4], tcol[4];
        #pragma unroll
        for (int a = 0; a < 4; a++) trow[a] = clampi(by0 + a, 0, 31) - by0;
        #pragma unroll
        for (int d = 0; d < 4; d++) tcol[d] = clampi(bx + d, 0, 31) - bx0;
        int coffT = ((h >> 2) - by0) * 21 + ((w >> 2) - bx0);

        float dotc[16];
        #pragma unroll
        for (int e = 0; e < 16; e++) dotc[e] = 0.f;

        #pragma unroll 4
        for (int cc = 0; cc < 16; cc++) {
            const float* Sx = sx + (l * 16 + cc) * 85;
            float cv = Sx[coffT];
            #pragma unroll
            for (int a = 0; a < 4; a++) {
                int rb = trow[a] * 21;
                #pragma unroll
                for (int d = 0; d < 4; d++)
                    dotc[a * 4 + d] = fmaf(Sx[rb + tcol[d]], cv, dotc[a * 4 + d]);
            }
        }
        #pragma unroll
        for (int e = 0; e < 16; e++) {
            dotc[e] += __shfl_xor(dotc[e], 1); dotc[e] += __shfl_xor(dotc[e], 2);
        }

        // cell norm = sum of 3 chunk partials (broadcast LDS reads)
        float cn_c = (scn3[coffT] + scn3[84 + coffT]) + scn3[168 + coffT];
        float nc2 = 1.f / fmaxf(sqrtf(cn_c), EPSC);
        float scell[16];
        #pragma unroll
        for (int a = 0; a < 4; a++) {
            #pragma unroll
            for (int d = 0; d < 4; d++) {
                int x = trow[a] * 21 + tcol[d];
                float cn_u = (scn3[x] + scn3[84 + x]) + scn3[168 + x];
                float nu = fmaxf(sqrtf(cn_u), EPSC);
                scell[a * 4 + d] = dotc[a * 4 + d] * nc2 / nu;
            }
        }

        // ---------- Phase 2: 49 sims; neg pair stores NEGATED values ----------
        const int QA[7] = {0, 0, 1, 1, 2, 2, 3};
        const int QB[7] = {0, 1, 1, 2, 2, 3, 3};
        bool ry = (h & 3) >= 2, rx = (w & 3) >= 2;

        float sims[49];
        #pragma unroll
        for (int i = 0; i < 7; i++) {
            int py = h + 2 * i - 6;
            bool vy = (unsigned)py < 128u;
            float srow[4];
            #pragma unroll
            for (int d = 0; d < 4; d++)
                srow[d] = ry ? scell[QA[i] * 4 + d] : scell[QB[i] * 4 + d];
            #pragma unroll
            for (int j = 0; j < 7; j++) {
                int px = w + 2 * j - 6;
                bool vx = (unsigned)px < 128u;
                float v = rx ? srow[QA[j]] : srow[QB[j]];
                float sv = (vy && vx) ? v : 0.f;
                sims[i * 7 + j] = posH ? sv : -sv;
            }
        }

        // ---------- Phase 3: pair-split 9-round scan (exact tie semantics) ----
        float hv[25];
        #pragma unroll
        for (int kk = 0; kk < 25; kk++) {
            float aa = sims[kk];
            float bb = (kk < 24) ? sims[25 + kk] : -3.4e38f;
            hv[kk] = lc ? bb : aa;
        }
        int k0 = lc * 25;
        {
            unsigned mymask = 0u;
            #pragma unroll
            for (int t = 0; t < 9; t++) {
                float best = -3.4e38f; int bkk = 30;
                #pragma unroll
                for (int kk = 0; kk < 25; kk++) {
                    if (!((mymask >> kk) & 1u) && hv[kk] > best) { best = hv[kk]; bkk = kk; }
                }
                int bi = k0 + bkk;
                float ov = __shfl_xor(best, 1);
                int   oi = __shfl_xor(bi, 1);
                if (ov > best || (ov == best && oi < bi)) { best = ov; bi = oi; }
                vsel[t] = best; isel[t] = bi;
                int rel = bi - k0;
                if ((unsigned)rel < 25u) mymask |= 1u << rel;
            }
        }
    }

    // ---------- Deferred ema tile write (loads have long completed) ----------
    #pragma unroll
    for (int r = 0; r < 24; r++) {
        int idx = tid + r * 256;
        if (idx < NC * 320) {
            int c = idx / 320; int rr = idx - c * 320;
            se[c * 321 + rr] = ereg[r];
        }
    }
    __syncthreads();

    if (active) {
        // ---------- Phase 4: gather from LDS ema tile, 10 classes/lane --------
        float av[10];
        #pragma unroll
        for (int jc = 0; jc < 10; jc++) av[jc] = 0.f;

        #pragma unroll
        for (int t = 0; t < 9; t++) {
            if (posH || t < 8) {
                int k = isel[t];
                float val = posH ? vsel[t] : -vsel[t];
                int i = (k * 586) >> 12; int j = k - 7 * i;
                int py = h + 2 * i - 6, px = w + 2 * j - 6;
                if ((unsigned)py < 128u && (unsigned)px < 128u) {
                    int iy0 = (py - 1) >> 1; float ty = (py & 1) ? 0.25f : 0.75f;
                    int ix0 = (px - 1) >> 1; float txx = (px & 1) ? 0.25f : 0.75f;
                    int y0 = clampi(iy0, 0, 63), y1 = clampi(iy0 + 1, 0, 63);
                    int x0 = clampi(ix0, 0, 63), x1 = clampi(ix0 + 1, 0, 63);
                    float w00 = (1.f - ty) * (1.f - txx), w01 = (1.f - ty) * txx;
                    float w10 = ty * (1.f - txx),         w11 = ty * txx;
                    int o00 = (y0 - ey0) * 40 + (x0 - ex0), o01 = (y0 - ey0) * 40 + (x1 - ex0);
                    int o10 = (y1 - ey0) * 40 + (x0 - ex0), o11 = (y1 - ey0) * 40 + (x1 - ex0);
                    #pragma unroll
                    for (int jc = 0; jc < 10; jc++) {
                        int c = lc + 2 * jc;
                        if (c < NC) {
                            const float* Sc = se + c * 321;
                            float g = w00 * Sc[o00] + w01 * Sc[o01]
                                    + w10 * Sc[o10] + w11 * Sc[o11];
                            av[jc] = fmaf(val, g, av[jc]);
                        }
                    }
                }
            }
        }

        // ---------- Phase 5: softmax + BCE within each pair ----------
        float m = -3.4e38f;
        #pragma unroll
        for (int jc = 0; jc < 10; jc++) {
            int c = lc + 2 * jc;
            if (c < NC) m = fmaxf(m, av[jc]);
        }
        m = fmaxf(m, __shfl_xor(m, 1));

        float Z = 0.f, S = 0.f, Bs = 0.f;
        #pragma unroll
        for (int jc = 0; jc < 10; jc++) {
            int c = lc + 2 * jc;
            if (c < NC) {
                float x = tx[jc];
                float e = expf(av[jc] - m); Z += e; S += e * x;
                float ls = fminf(x, 0.f) - log1pf(expf(-fabsf(x)));  // log_sigmoid
                Bs += x - ls;
            }
        }
        Z += __shfl_xor(Z, 1); S += __shfl_xor(S, 1); Bs += __shfl_xor(Bs, 1);

        float res = posH ? (Bs - S / Z) : (S / Z - Bs);
        float oth = __shfl_xor(res, 2);       // lane 0 <- lane 2's neg result
        lp = (l == 0) ? res : 0.f;            // sum_c bce(x, pl_pos)
        ln = (l == 0) ? oth : 0.f;            // sum_c -bce(x, pl_neg)
    }

    // ---------- Wave reduce, block reduce, per-block partial store ----------
    #pragma unroll
    for (int off = 32; off > 0; off >>= 1) {
        lp += __shfl_down(lp, off);
        ln += __shfl_down(ln, off);
        cm += __shfl_down(cm, off);
    }
    int wid = tid >> 6;
    if ((tid & 63) == 0) { red[wid][0] = lp; red[wid][1] = ln; red[wid][2] = cm; }
    __syncthreads();
    if (tid == 0) {
        float* pb = part + 3 * blockIdx.x;
        pb[0] = red[0][0] + red[1][0] + red[2][0] + red[3][0];
        pb[1] = red[0][1] + red[1][1] + red[2][1] + red[3][1];
        pb[2] = red[0][2] + red[1][2] + red[2][2] + red[3][2];
        __threadfence();                       // publish partials device-wide
        unsigned prev = atomicAdd(done, 1u);   // device-coherent
        lastflag = (prev == NBLK - 1) ? 1 : 0;
    }
    __syncthreads();

    // ---------- Last block: final reduction + output (same order as R29) -----
    if (lastflag) {
        __threadfence();                       // acquire
        int t = tid;
        float a  = part[3 * t + 0] + part[3 * (t + 256) + 0];
        float bb = part[3 * t + 1] + part[3 * (t + 256) + 1];
        float c  = part[3 * t + 2] + part[3 * (t + 256) + 2];
        #pragma unroll
        for (int off = 32; off > 0; off >>= 1) {
            a  += __shfl_down(a, off);
            bb += __shfl_down(bb, off);
            c  += __shfl_down(c, off);
        }
        if ((t & 63) == 0) { red[wid][0] = a; red[wid][1] = bb; red[wid][2] = c; }
        __syncthreads();
        if (t == 0) {
            float a0 = red[0][0] + red[1][0] + red[2][0] + red[3][0];
            float a1 = red[0][1] + red[1][1] + red[2][1] + red[3][1];
            float a2 = red[0][2] + red[1][2] + red[2][2] + red[3][2];
            float denom = a2 * (float)NC;
            out[0] = a0 / denom;              // loss_pos * W_POS(=1.0)
            out[1] = a1 / denom * 0.1f;       // loss_neg * W_NEG(=0.1)
        }
    }
}

extern "C" void kernel_launch(void* const* d_in, const int* in_sizes, int n_in,
                              void* d_out, int out_size, void* d_ws, size_t ws_size,
                              hipStream_t stream) {
    const float* trg = (const float*)d_in[0];   // [2,19,128,128]
    const float* ema = (const float*)d_in[1];   // [2,19,64,64]
    const float* xe  = (const float*)d_in[2];   // [2,64,32,32]
    const float* mix = (const float*)d_in[3];   // [2,1,128,128]
    unsigned* done = (unsigned*)d_ws;
    float* part = (float*)((char*)d_ws + WS_PART_OFF);
    float* out  = (float*)d_out;

    hipMemsetAsync(done, 0, sizeof(unsigned), stream);   // graph-legal reset
    hipLaunchKernelGGL(pfst_main, dim3(NBLK), dim3(256), 0, stream,
                       trg, ema, xe, mix, done, part, out);
}

// Round 31
// 33.901 us; speedup vs baseline: 1.2683x; 1.2683x over previous
//
#include <hip/hip_runtime.h>
#include <math.h>

// Problem constants
#define NB 2
#define NC 19      // classes
#define NH 128
#define NW 128
#define NCF 64     // feature channels
#define NHE 64     // ema logits H/W
#define NHX 32     // x_ema H/W
#define EPSC 1e-8f
#define NBLK 512   // pfst_main grid size

// d_ws: part[NBLK*3] f32 @64
#define WS_PART_OFF 64

__device__ __forceinline__ int clampi(int v, int lo, int hi) {
    return v < lo ? lo : (v > hi ? hi : v);
}

// R29 champion (33.76us). 4 lanes/pixel: lanes 0-1 pos / 2-3 neg (scan on
// -sims, IEEE-exact mirror of top_k(-sim)); pair-split 25/24-tap selection
// scan with shfl (max, lowest-index) combine; parallel 3-chunk in-block cell
// norms (replaces pfst_norm kernel); T14 async-stage (ema regs->LDS write
// deferred past phases 1-3 so global latency hides under compute).
// NOTE (R26/R30): single-kernel fence+atomic completion costs ~9us here —
// the separate tiny pfst_final dispatch is the cheaper pattern on MI355X.
__global__ __launch_bounds__(256) void pfst_main(
    const float* __restrict__ trg, const float* __restrict__ ema,
    const float* __restrict__ xe,  const float* __restrict__ mix,
    float* __restrict__ part)
{
    __shared__ float se[NC * 321];        // ema tile [19][8][40], stride 321 (pad)
    __shared__ float sx[NCF * 85];        // xe tile [64][4][21], stride 85 (pad)
    __shared__ float scn3[3 * 84];        // partial cell norms [3 chunks][84]
    __shared__ float red[4][3];

    int tid = threadIdx.x;
    int l = tid & 3;                      // lane in quad
    int lc = l & 1;                       // scan-half / class-lane within pair
    bool posH = (l < 2);                  // pair role
    int q = tid >> 2;                     // pixel slot (0..63)
    int p0 = blockIdx.x * 64;
    int b = p0 >> 14;
    int h = (p0 >> 7) & 127;              // block-uniform
    int w0 = p0 & 127;                    // 0 or 64
    int w = w0 + q;

    int ey0 = (h - 7) >> 1, ex0 = (w0 - 7) >> 1;   // ema tile origin
    int by0 = (h - 6) >> 2, bx0 = (w0 - 6) >> 2;   // cell tile origin

    // ---------- Stage: xe->regs first, then ema->regs (issue order!) ----------
    float xreg[21];
    {
        const float* Xb = xe + b * (NCF * NHX * NHX);
        #pragma unroll
        for (int r = 0; r < 21; r++) {
            int idx = tid + r * 256;      // < 5376 always
            int ch = idx / 84; int rr = idx - ch * 84;
            int a = rr / 21;   int d = rr - a * 21;
            int gy = clampi(by0 + a, 0, 31), gx = clampi(bx0 + d, 0, 31);
            xreg[r] = Xb[ch * (NHX * NHX) + gy * 32 + gx];
        }
    }
    float ereg[24];
    {
        const float* Eb = ema + b * NC * (NHE * NHE);
        #pragma unroll
        for (int r = 0; r < 24; r++) {
            int idx = tid + r * 256;      // < 6144; valid < 6080
            if (idx < NC * 320) {
                int c = idx / 320; int rr = idx - c * 320;
                int rw = rr / 40;  int x = rr - rw * 40;
                int gy = clampi(ey0 + rw, 0, 63), gx = clampi(ex0 + x, 0, 63);
                ereg[r] = Eb[c * (NHE * NHE) + gy * 64 + gx];
            } else ereg[r] = 0.f;
        }
    }
    // Write xe to LDS (waits only on xe loads; ema loads stay in flight)
    #pragma unroll
    for (int r = 0; r < 21; r++) {
        int idx = tid + r * 256;
        int ch = idx / 84; int rr = idx - ch * 84;
        sx[ch * 85 + rr] = xreg[r];
    }
    __syncthreads();

    // ---------- In-block cell norms: 3-chunk parallel split ----------
    // Thread t<252: cell = t%84, chunk = t/84 covers 21-22 channels.
    // Consecutive lanes -> consecutive cells -> consecutive banks (no conflict).
    if (tid < 252) {
        int cell = tid % 84;
        int chunk = tid / 84;
        int ch0 = chunk * 21;
        int nch = (chunk == 2) ? 22 : 21;
        float s = 0.f;
        #pragma unroll
        for (int cc = 0; cc < 22; cc++) {
            if (cc < nch) {
                float v = sx[(ch0 + cc) * 85 + cell];
                s = fmaf(v, v, s);
            }
        }
        scn3[chunk * 84 + cell] = s;
    }
    __syncthreads();

    float mval = mix[(b << 14) + (h << 7) + w];
    bool active = mval < 0.5f;            // (1 - mix) > 0.5
    float lp = 0.f, ln = 0.f;
    float cm = (active && l == 0) ? 1.f : 0.f;

    float tx[10];
    float vsel[9]; int isel[9];

    if (active) {
        // ---------- Prefetch trg for this lane's 10 classes ----------
        const float* Tb = trg + b * NC * (NH * NW) + (h << 7) + w;
        #pragma unroll
        for (int jc = 0; jc < 10; jc++) {
            int c = lc + 2 * jc;
            tx[jc] = (c < NC) ? Tb[c * (NH * NW)] : 0.f;
        }

        // ---------- Phase 1: cell dots from LDS, 16 channels/lane ----------
        int bx = (w - 6) >> 2;
        int trow[4], tcol[4];
        #pragma unroll
        for (int a = 0; a < 4; a++) trow[a] = clampi(by0 + a, 0, 31) - by0;
        #pragma unroll
        for (int d = 0; d < 4; d++) tcol[d] = clampi(bx + d, 0, 31) - bx0;
        int coffT = ((h >> 2) - by0) * 21 + ((w >> 2) - bx0);

        float dotc[16];
        #pragma unroll
        for (int e = 0; e < 16; e++) dotc[e] = 0.f;

        #pragma unroll 4
        for (int cc = 0; cc < 16; cc++) {
            const float* Sx = sx + (l * 16 + cc) * 85;
            float cv = Sx[coffT];
            #pragma unroll
            for (int a = 0; a < 4; a++) {
                int rb = trow[a] * 21;
                #pragma unroll
                for (int d = 0; d < 4; d++)
                    dotc[a * 4 + d] = fmaf(Sx[rb + tcol[d]], cv, dotc[a * 4 + d]);
            }
        }
        #pragma unroll
        for (int e = 0; e < 16; e++) {
            dotc[e] += __shfl_xor(dotc[e], 1); dotc[e] += __shfl_xor(dotc[e], 2);
        }

        // cell norm = sum of 3 chunk partials (broadcast LDS reads)
        float cn_c = (scn3[coffT] + scn3[84 + coffT]) + scn3[168 + coffT];
        float nc2 = 1.f / fmaxf(sqrtf(cn_c), EPSC);
        float scell[16];
        #pragma unroll
        for (int a = 0; a < 4; a++) {
            #pragma unroll
            for (int d = 0; d < 4; d++) {
                int x = trow[a] * 21 + tcol[d];
                float cn_u = (scn3[x] + scn3[84 + x]) + scn3[168 + x];
                float nu = fmaxf(sqrtf(cn_u), EPSC);
                scell[a * 4 + d] = dotc[a * 4 + d] * nc2 / nu;
            }
        }

        // ---------- Phase 2: 49 sims; neg pair stores NEGATED values ----------
        const int QA[7] = {0, 0, 1, 1, 2, 2, 3};
        const int QB[7] = {0, 1, 1, 2, 2, 3, 3};
        bool ry = (h & 3) >= 2, rx = (w & 3) >= 2;

        float sims[49];
        #pragma unroll
        for (int i = 0; i < 7; i++) {
            int py = h + 2 * i - 6;
            bool vy = (unsigned)py < 128u;
            float srow[4];
            #pragma unroll
            for (int d = 0; d < 4; d++)
                srow[d] = ry ? scell[QA[i] * 4 + d] : scell[QB[i] * 4 + d];
            #pragma unroll
            for (int j = 0; j < 7; j++) {
                int px = w + 2 * j - 6;
                bool vx = (unsigned)px < 128u;
                float v = rx ? srow[QA[j]] : srow[QB[j]];
                float sv = (vy && vx) ? v : 0.f;
                sims[i * 7 + j] = posH ? sv : -sv;
            }
        }

        // ---------- Phase 3: pair-split 9-round scan (exact tie semantics) ----
        float hv[25];
        #pragma unroll
        for (int kk = 0; kk < 25; kk++) {
            float aa = sims[kk];
            float bb = (kk < 24) ? sims[25 + kk] : -3.4e38f;
            hv[kk] = lc ? bb : aa;
        }
        int k0 = lc * 25;
        {
            unsigned mymask = 0u;
            #pragma unroll
            for (int t = 0; t < 9; t++) {
                float best = -3.4e38f; int bkk = 30;
                #pragma unroll
                for (int kk = 0; kk < 25; kk++) {
                    if (!((mymask >> kk) & 1u) && hv[kk] > best) { best = hv[kk]; bkk = kk; }
                }
                int bi = k0 + bkk;
                float ov = __shfl_xor(best, 1);
                int   oi = __shfl_xor(bi, 1);
                if (ov > best || (ov == best && oi < bi)) { best = ov; bi = oi; }
                vsel[t] = best; isel[t] = bi;
                int rel = bi - k0;
                if ((unsigned)rel < 25u) mymask |= 1u << rel;
            }
        }
    }

    // ---------- Deferred ema tile write (loads have long completed) ----------
    #pragma unroll
    for (int r = 0; r < 24; r++) {
        int idx = tid + r * 256;
        if (idx < NC * 320) {
            int c = idx / 320; int rr = idx - c * 320;
            se[c * 321 + rr] = ereg[r];
        }
    }
    __syncthreads();

    if (active) {
        // ---------- Phase 4: gather from LDS ema tile, 10 classes/lane --------
        float av[10];
        #pragma unroll
        for (int jc = 0; jc < 10; jc++) av[jc] = 0.f;

        #pragma unroll
        for (int t = 0; t < 9; t++) {
            if (posH || t < 8) {
                int k = isel[t];
                float val = posH ? vsel[t] : -vsel[t];
                int i = (k * 586) >> 12; int j = k - 7 * i;
                int py = h + 2 * i - 6, px = w + 2 * j - 6;
                if ((unsigned)py < 128u && (unsigned)px < 128u) {
                    int iy0 = (py - 1) >> 1; float ty = (py & 1) ? 0.25f : 0.75f;
                    int ix0 = (px - 1) >> 1; float txx = (px & 1) ? 0.25f : 0.75f;
                    int y0 = clampi(iy0, 0, 63), y1 = clampi(iy0 + 1, 0, 63);
                    int x0 = clampi(ix0, 0, 63), x1 = clampi(ix0 + 1, 0, 63);
                    float w00 = (1.f - ty) * (1.f - txx), w01 = (1.f - ty) * txx;
                    float w10 = ty * (1.f - txx),         w11 = ty * txx;
                    int o00 = (y0 - ey0) * 40 + (x0 - ex0), o01 = (y0 - ey0) * 40 + (x1 - ex0);
                    int o10 = (y1 - ey0) * 40 + (x0 - ex0), o11 = (y1 - ey0) * 40 + (x1 - ex0);
                    #pragma unroll
                    for (int jc = 0; jc < 10; jc++) {
                        int c = lc + 2 * jc;
                        if (c < NC) {
                            const float* Sc = se + c * 321;
                            float g = w00 * Sc[o00] + w01 * Sc[o01]
                                    + w10 * Sc[o10] + w11 * Sc[o11];
                            av[jc] = fmaf(val, g, av[jc]);
                        }
                    }
                }
            }
        }

        // ---------- Phase 5: softmax + BCE within each pair ----------
        float m = -3.4e38f;
        #pragma unroll
        for (int jc = 0; jc < 10; jc++) {
            int c = lc + 2 * jc;
            if (c < NC) m = fmaxf(m, av[jc]);
        }
        m = fmaxf(m, __shfl_xor(m, 1));

        float Z = 0.f, S = 0.f, Bs = 0.f;
        #pragma unroll
        for (int jc = 0; jc < 10; jc++) {
            int c = lc + 2 * jc;
            if (c < NC) {
                float x = tx[jc];
                float e = expf(av[jc] - m); Z += e; S += e * x;
                float ls = fminf(x, 0.f) - log1pf(expf(-fabsf(x)));  // log_sigmoid
                Bs += x - ls;
            }
        }
        Z += __shfl_xor(Z, 1); S += __shfl_xor(S, 1); Bs += __shfl_xor(Bs, 1);

        float res = posH ? (Bs - S / Z) : (S / Z - Bs);
        float oth = __shfl_xor(res, 2);       // lane 0 <- lane 2's neg result
        lp = (l == 0) ? res : 0.f;            // sum_c bce(x, pl_pos)
        ln = (l == 0) ? oth : 0.f;            // sum_c -bce(x, pl_neg)
    }

    // ---------- Wave reduce, block reduce, per-block partial store ----------
    #pragma unroll
    for (int off = 32; off > 0; off >>= 1) {
        lp += __shfl_down(lp, off);
        ln += __shfl_down(ln, off);
        cm += __shfl_down(cm, off);
    }
    int wid = tid >> 6;
    if ((tid & 63) == 0) { red[wid][0] = lp; red[wid][1] = ln; red[wid][2] = cm; }
    __syncthreads();
    if (tid == 0) {
        float* pb = part + 3 * blockIdx.x;
        pb[0] = red[0][0] + red[1][0] + red[2][0] + red[3][0];
        pb[1] = red[0][1] + red[1][1] + red[2][1] + red[3][1];
        pb[2] = red[0][2] + red[1][2] + red[2][2] + red[3][2];
    }
}

// Final reduction of NBLK per-block partials (no atomics anywhere).
// Output: FLOAT32[2] = [loss_pos, 0.1*loss_neg] (decoded R0-R10, verified R11+).
__global__ __launch_bounds__(256) void pfst_final(const float* __restrict__ part,
                                                  float* __restrict__ out) {
    int t = threadIdx.x;
    float lp = part[3 * t + 0] + part[3 * (t + 256) + 0];
    float ln = part[3 * t + 1] + part[3 * (t + 256) + 1];
    float cm = part[3 * t + 2] + part[3 * (t + 256) + 2];
    #pragma unroll
    for (int off = 32; off > 0; off >>= 1) {
        lp += __shfl_down(lp, off);
        ln += __shfl_down(ln, off);
        cm += __shfl_down(cm, off);
    }
    __shared__ float red[4][3];
    int wid = t >> 6;
    if ((t & 63) == 0) { red[wid][0] = lp; red[wid][1] = ln; red[wid][2] = cm; }
    __syncthreads();
    if (t == 0) {
        float a0 = red[0][0] + red[1][0] + red[2][0] + red[3][0];
        float a1 = red[0][1] + red[1][1] + red[2][1] + red[3][1];
        float a2 = red[0][2] + red[1][2] + red[2][2] + red[3][2];
        float denom = a2 * (float)NC;
        out[0] = a0 / denom;              // loss_pos * W_POS(=1.0)
        out[1] = a1 / denom * 0.1f;       // loss_neg * W_NEG(=0.1)
    }
}

extern "C" void kernel_launch(void* const* d_in, const int* in_sizes, int n_in,
                              void* d_out, int out_size, void* d_ws, size_t ws_size,
                              hipStream_t stream) {
    const float* trg = (const float*)d_in[0];   // [2,19,128,128]
    const float* ema = (const float*)d_in[1];   // [2,19,64,64]
    const float* xe  = (const float*)d_in[2];   // [2,64,32,32]
    const float* mix = (const float*)d_in[3];   // [2,1,128,128]
    float* part = (float*)((char*)d_ws + WS_PART_OFF);
    float* out  = (float*)d_out;

    hipLaunchKernelGGL(pfst_main, dim3(NBLK), dim3(256), 0, stream,
                       trg, ema, xe, mix, part);
    hipLaunchKernelGGL(pfst_final, dim3(1), dim3(256), 0, stream, part, out);
}

// Round 32
// 31.238 us; speedup vs baseline: 1.3765x; 1.0853x over previous
//
#include <hip/hip_runtime.h>
#include <math.h>

// Problem constants
#define NB 2
#define NC 19      // classes
#define NH 128
#define NW 128
#define NCF 64     // feature channels
#define NHE 64     // ema logits H/W
#define NHX 32     // x_ema H/W
#define EPSC 1e-8f
#define NBLK 512   // pfst_main grid size

// d_ws: part[NBLK*3] f32 @64
#define WS_PART_OFF 64

__device__ __forceinline__ int clampi(int v, int lo, int hi) {
    return v < lo ? lo : (v > hi ? hi : v);
}

// R29 champion + even/odd pixel-pair sharing of phases 1-3 (bit-identical
// within pairs: w>>2, (w-6)>>2, (w&3)>=2 and tap validity all match — px
// parity equals w parity and both bounds are even). 8-lane groups: phase-1
// channels split 8-way; phase-3 pos scan on lanes 0-3 / neg on 4-7, each
// 4-way split (R23-proven scan); selections exchanged via shfl_xor(4).
__global__ __launch_bounds__(256) void pfst_main(
    const float* __restrict__ trg, const float* __restrict__ ema,
    const float* __restrict__ xe,  const float* __restrict__ mix,
    float* __restrict__ part)
{
    __shared__ float se[NC * 321];        // ema tile [19][8][40], stride 321 (pad)
    __shared__ float sx[NCF * 85];        // xe tile [64][4][21], stride 85 (pad)
    __shared__ float scn3[3 * 84];        // partial cell norms [3 chunks][84]
    __shared__ float red[4][3];

    int tid = threadIdx.x;
    int l = tid & 3;                      // lane in pixel quad
    int u = tid & 7;                      // lane in pair octet
    int lc = l & 1;                       // class-lane within pos/neg pair
    bool posH = (l < 2);                  // phase-4/5 role (per pixel)
    int q = tid >> 2;                     // pixel slot (0..63)
    int p0 = blockIdx.x * 64;
    int b = p0 >> 14;
    int h = (p0 >> 7) & 127;              // block-uniform
    int w0 = p0 & 127;                    // 0 or 64
    int w = w0 + q;

    int ey0 = (h - 7) >> 1, ex0 = (w0 - 7) >> 1;   // ema tile origin
    int by0 = (h - 6) >> 2, bx0 = (w0 - 6) >> 2;   // cell tile origin

    // ---------- Stage: xe->regs first, then ema->regs (issue order!) ----------
    float xreg[21];
    {
        const float* Xb = xe + b * (NCF * NHX * NHX);
        #pragma unroll
        for (int r = 0; r < 21; r++) {
            int idx = tid + r * 256;      // < 5376 always
            int ch = idx / 84; int rr = idx - ch * 84;
            int a = rr / 21;   int d = rr - a * 21;
            int gy = clampi(by0 + a, 0, 31), gx = clampi(bx0 + d, 0, 31);
            xreg[r] = Xb[ch * (NHX * NHX) + gy * 32 + gx];
        }
    }
    float ereg[24];
    {
        const float* Eb = ema + b * NC * (NHE * NHE);
        #pragma unroll
        for (int r = 0; r < 24; r++) {
            int idx = tid + r * 256;      // < 6144; valid < 6080
            if (idx < NC * 320) {
                int c = idx / 320; int rr = idx - c * 320;
                int rw = rr / 40;  int x = rr - rw * 40;
                int gy = clampi(ey0 + rw, 0, 63), gx = clampi(ex0 + x, 0, 63);
                ereg[r] = Eb[c * (NHE * NHE) + gy * 64 + gx];
            } else ereg[r] = 0.f;
        }
    }
    // Write xe to LDS (waits only on xe loads; ema loads stay in flight)
    #pragma unroll
    for (int r = 0; r < 21; r++) {
        int idx = tid + r * 256;
        int ch = idx / 84; int rr = idx - ch * 84;
        sx[ch * 85 + rr] = xreg[r];
    }
    __syncthreads();

    // ---------- In-block cell norms: 3-chunk parallel split ----------
    if (tid < 252) {
        int cell = tid % 84;
        int chunk = tid / 84;
        int ch0 = chunk * 21;
        int nch = (chunk == 2) ? 22 : 21;
        float s = 0.f;
        #pragma unroll
        for (int cc = 0; cc < 22; cc++) {
            if (cc < nch) {
                float v = sx[(ch0 + cc) * 85 + cell];
                s = fmaf(v, v, s);
            }
        }
        scn3[chunk * 84 + cell] = s;
    }
    __syncthreads();

    float mval = mix[(b << 14) + (h << 7) + w];
    bool active = mval < 0.5f;            // (1 - mix) > 0.5
    // pair-any-active (pair-uniform: active is identical across a pixel's quad)
    float af = active ? 1.f : 0.f;
    af += __shfl_xor(af, 4);
    bool apair = (af > 0.f);

    float lp = 0.f, ln = 0.f;
    float cm = (active && l == 0) ? 1.f : 0.f;

    float tx[10];
    float vsel[9]; int isel[9];

    if (active) {
        // ---------- Prefetch trg for this lane's 10 classes ----------
        const float* Tb = trg + b * NC * (NH * NW) + (h << 7) + w;
        #pragma unroll
        for (int jc = 0; jc < 10; jc++) {
            int c = lc + 2 * jc;
            tx[jc] = (c < NC) ? Tb[c * (NH * NW)] : 0.f;
        }
    }

    if (apair) {
        // ---------- Phase 1: cell dots, 8 channels/lane across the pair -------
        int bx = (w - 6) >> 2;
        int trow[4], tcol[4];
        #pragma unroll
        for (int a = 0; a < 4; a++) trow[a] = clampi(by0 + a, 0, 31) - by0;
        #pragma unroll
        for (int d = 0; d < 4; d++) tcol[d] = clampi(bx + d, 0, 31) - bx0;
        int coffT = ((h >> 2) - by0) * 21 + ((w >> 2) - bx0);   // pair-identical

        float dotc[16];
        #pragma unroll
        for (int e = 0; e < 16; e++) dotc[e] = 0.f;

        #pragma unroll
        for (int cc = 0; cc < 8; cc++) {
            const float* Sx = sx + (u * 8 + cc) * 85;
            float cv = Sx[coffT];
            #pragma unroll
            for (int a = 0; a < 4; a++) {
                int rb = trow[a] * 21;
                #pragma unroll
                for (int d = 0; d < 4; d++)
                    dotc[a * 4 + d] = fmaf(Sx[rb + tcol[d]], cv, dotc[a * 4 + d]);
            }
        }
        #pragma unroll
        for (int e = 0; e < 16; e++) {
            dotc[e] += __shfl_xor(dotc[e], 1);
            dotc[e] += __shfl_xor(dotc[e], 2);
            dotc[e] += __shfl_xor(dotc[e], 4);
        }

        // cell norm = sum of 3 chunk partials (broadcast LDS reads)
        float cn_c = (scn3[coffT] + scn3[84 + coffT]) + scn3[168 + coffT];
        float nc2 = 1.f / fmaxf(sqrtf(cn_c), EPSC);
        float scell[16];
        #pragma unroll
        for (int a = 0; a < 4; a++) {
            #pragma unroll
            for (int d = 0; d < 4; d++) {
                int x = trow[a] * 21 + tcol[d];
                float cn_u = (scn3[x] + scn3[84 + x]) + scn3[168 + x];
                float nu = fmaxf(sqrtf(cn_u), EPSC);
                scell[a * 4 + d] = dotc[a * 4 + d] * nc2 / nu;
            }
        }

        // ---------- Phase 2: 49 sims (pair-identical); lanes 4-7 NEGATED ------
        const int QA[7] = {0, 0, 1, 1, 2, 2, 3};
        const int QB[7] = {0, 1, 1, 2, 2, 3, 3};
        bool ry = (h & 3) >= 2, rx = (w & 3) >= 2;   // rx pair-identical
        bool posScan = (u < 4);

        float sims[49];
        #pragma unroll
        for (int i = 0; i < 7; i++) {
            int py = h + 2 * i - 6;
            bool vy = (unsigned)py < 128u;
            float srow[4];
            #pragma unroll
            for (int d = 0; d < 4; d++)
                srow[d] = ry ? scell[QA[i] * 4 + d] : scell[QB[i] * 4 + d];
            #pragma unroll
            for (int j = 0; j < 7; j++) {
                int px = w + 2 * j - 6;
                bool vx = (unsigned)px < 128u;   // pair-identical predicate
                float v = rx ? srow[QA[j]] : srow[QB[j]];
                float sv = (vy && vx) ? v : 0.f;
                sims[i * 7 + j] = posScan ? sv : -sv;
            }
        }

        // ---------- Phase 3: 4-way-split 9-round scan per half (R23-proven) ---
        int s4 = u & 3;                   // scan-lane within half
        float hv[13];
        #pragma unroll
        for (int kk = 0; kk < 13; kk++) {
            float v0 = (kk < 12) ? sims[kk]      : -3.4e38f;
            float v1 = (kk < 12) ? sims[12 + kk] : -3.4e38f;
            float v2 = (kk < 12) ? sims[24 + kk] : -3.4e38f;
            float v3 = sims[36 + kk];
            float lo = (s4 & 1) ? v1 : v0;
            float hi = (s4 & 1) ? v3 : v2;
            hv[kk] = (s4 & 2) ? hi : lo;
        }
        int k0 = s4 * 12;
        int nown = (s4 == 3) ? 13 : 12;
        {
            unsigned mymask = 0u;
            #pragma unroll
            for (int t = 0; t < 9; t++) {
                float best = -3.4e38f; int bkk = 20;
                #pragma unroll
                for (int kk = 0; kk < 13; kk++) {
                    if (!((mymask >> kk) & 1u) && hv[kk] > best) { best = hv[kk]; bkk = kk; }
                }
                int bi = k0 + bkk;
                #pragma unroll
                for (int st = 1; st <= 2; st <<= 1) {
                    float ov = __shfl_xor(best, st);
                    int   oi = __shfl_xor(bi, st);
                    if (ov > best || (ov == best && oi < bi)) { best = ov; bi = oi; }
                }
                vsel[t] = best; isel[t] = bi;
                int rel = bi - k0;
                if ((unsigned)rel < (unsigned)nown) mymask |= 1u << rel;
            }
        }

        // ---------- Exchange: each lane takes the selection its 4-5 role needs.
        // Lane needs pos iff (l<2); lane computed pos iff (u<4).
        bool useOwn = ((u < 4) == (l < 2));
        #pragma unroll
        for (int t = 0; t < 9; t++) {
            float ov = __shfl_xor(vsel[t], 4);
            int   oi = __shfl_xor(isel[t], 4);
            vsel[t] = useOwn ? vsel[t] : ov;
            isel[t] = useOwn ? isel[t] : oi;
        }
    }

    // ---------- Deferred ema tile write (loads have long completed) ----------
    #pragma unroll
    for (int r = 0; r < 24; r++) {
        int idx = tid + r * 256;
        if (idx < NC * 320) {
            int c = idx / 320; int rr = idx - c * 320;
            se[c * 321 + rr] = ereg[r];
        }
    }
    __syncthreads();

    if (active) {
        // ---------- Phase 4: gather from LDS ema tile, 10 classes/lane --------
        float av[10];
        #pragma unroll
        for (int jc = 0; jc < 10; jc++) av[jc] = 0.f;

        #pragma unroll
        for (int t = 0; t < 9; t++) {
            if (posH || t < 8) {
                int k = isel[t];
                float val = posH ? vsel[t] : -vsel[t];
                int i = (k * 586) >> 12; int j = k - 7 * i;
                int py = h + 2 * i - 6, px = w + 2 * j - 6;
                if ((unsigned)py < 128u && (unsigned)px < 128u) {
                    int iy0 = (py - 1) >> 1; float ty = (py & 1) ? 0.25f : 0.75f;
                    int ix0 = (px - 1) >> 1; float txx = (px & 1) ? 0.25f : 0.75f;
                    int y0 = clampi(iy0, 0, 63), y1 = clampi(iy0 + 1, 0, 63);
                    int x0 = clampi(ix0, 0, 63), x1 = clampi(ix0 + 1, 0, 63);
                    float w00 = (1.f - ty) * (1.f - txx), w01 = (1.f - ty) * txx;
                    float w10 = ty * (1.f - txx),         w11 = ty * txx;
                    int o00 = (y0 - ey0) * 40 + (x0 - ex0), o01 = (y0 - ey0) * 40 + (x1 - ex0);
                    int o10 = (y1 - ey0) * 40 + (x0 - ex0), o11 = (y1 - ey0) * 40 + (x1 - ex0);
                    #pragma unroll
                    for (int jc = 0; jc < 10; jc++) {
                        int c = lc + 2 * jc;
                        if (c < NC) {
                            const float* Sc = se + c * 321;
                            float g = w00 * Sc[o00] + w01 * Sc[o01]
                                    + w10 * Sc[o10] + w11 * Sc[o11];
                            av[jc] = fmaf(val, g, av[jc]);
                        }
                    }
                }
            }
        }

        // ---------- Phase 5: softmax + BCE within each pos/neg pair ----------
        float m = -3.4e38f;
        #pragma unroll
        for (int jc = 0; jc < 10; jc++) {
            int c = lc + 2 * jc;
            if (c < NC) m = fmaxf(m, av[jc]);
        }
        m = fmaxf(m, __shfl_xor(m, 1));

        float Z = 0.f, S = 0.f, Bs = 0.f;
        #pragma unroll
        for (int jc = 0; jc < 10; jc++) {
            int c = lc + 2 * jc;
            if (c < NC) {
                float x = tx[jc];
                float e = expf(av[jc] - m); Z += e; S += e * x;
                float ls = fminf(x, 0.f) - log1pf(expf(-fabsf(x)));  // log_sigmoid
                Bs += x - ls;
            }
        }
        Z += __shfl_xor(Z, 1); S += __shfl_xor(S, 1); Bs += __shfl_xor(Bs, 1);

        float res = posH ? (Bs - S / Z) : (S / Z - Bs);
        float oth = __shfl_xor(res, 2);       // lane 0 <- lane 2's neg result
        lp = (l == 0) ? res : 0.f;            // sum_c bce(x, pl_pos)
        ln = (l == 0) ? oth : 0.f;            // sum_c -bce(x, pl_neg)
    }

    // ---------- Wave reduce, block reduce, per-block partial store ----------
    #pragma unroll
    for (int off = 32; off > 0; off >>= 1) {
        lp += __shfl_down(lp, off);
        ln += __shfl_down(ln, off);
        cm += __shfl_down(cm, off);
    }
    int wid = tid >> 6;
    if ((tid & 63) == 0) { red[wid][0] = lp; red[wid][1] = ln; red[wid][2] = cm; }
    __syncthreads();
    if (tid == 0) {
        float* pb = part + 3 * blockIdx.x;
        pb[0] = red[0][0] + red[1][0] + red[2][0] + red[3][0];
        pb[1] = red[0][1] + red[1][1] + red[2][1] + red[3][1];
        pb[2] = red[0][2] + red[1][2] + red[2][2] + red[3][2];
    }
}

// Final reduction of NBLK per-block partials (no atomics anywhere).
// Output: FLOAT32[2] = [loss_pos, 0.1*loss_neg] (decoded R0-R10, verified R11+).
__global__ __launch_bounds__(256) void pfst_final(const float* __restrict__ part,
                                                  float* __restrict__ out) {
    int t = threadIdx.x;
    float lp = part[3 * t + 0] + part[3 * (t + 256) + 0];
    float ln = part[3 * t + 1] + part[3 * (t + 256) + 1];
    float cm = part[3 * t + 2] + part[3 * (t + 256) + 2];
    #pragma unroll
    for (int off = 32; off > 0; off >>= 1) {
        lp += __shfl_down(lp, off);
        ln += __shfl_down(ln, off);
        cm += __shfl_down(cm, off);
    }
    __shared__ float red[4][3];
    int wid = t >> 6;
    if ((t & 63) == 0) { red[wid][0] = lp; red[wid][1] = ln; red[wid][2] = cm; }
    __syncthreads();
    if (t == 0) {
        float a0 = red[0][0] + red[1][0] + red[2][0] + red[3][0];
        float a1 = red[0][1] + red[1][1] + red[2][1] + red[3][1];
        float a2 = red[0][2] + red[1][2] + red[2][2] + red[3][2];
        float denom = a2 * (float)NC;
        out[0] = a0 / denom;              // loss_pos * W_POS(=1.0)
        out[1] = a1 / denom * 0.1f;       // loss_neg * W_NEG(=0.1)
    }
}

extern "C" void kernel_launch(void* const* d_in, const int* in_sizes, int n_in,
                              void* d_out, int out_size, void* d_ws, size_t ws_size,
                              hipStream_t stream) {
    const float* trg = (const float*)d_in[0];   // [2,19,128,128]
    const float* ema = (const float*)d_in[1];   // [2,19,64,64]
    const float* xe  = (const float*)d_in[2];   // [2,64,32,32]
    const float* mix = (const float*)d_in[3];   // [2,1,128,128]
    float* part = (float*)((char*)d_ws + WS_PART_OFF);
    float* out  = (float*)d_out;

    hipLaunchKernelGGL(pfst_main, dim3(NBLK), dim3(256), 0, stream,
                       trg, ema, xe, mix, part);
    hipLaunchKernelGGL(pfst_final, dim3(1), dim3(256), 0, stream, part, out);
}

// Round 33
// 31.036 us; speedup vs baseline: 1.3854x; 1.0065x over previous
//
#include <hip/hip_runtime.h>
#include <math.h>

// Problem constants
#define NB 2
#define NC 19      // classes
#define NH 128
#define NW 128
#define NCF 64     // feature channels
#define NHE 64     // ema logits H/W
#define NHX 32     // x_ema H/W
#define EPSC 1e-8f
#define NBLK 512   // pfst_main grid size

// d_ws: part[NBLK*3] f32 @64
#define WS_PART_OFF 64

__device__ __forceinline__ int clampi(int v, int lo, int hi) {
    return v < lo ? lo : (v > hi ? hi : v);
}

// R32 champion + 2-row blocks (32w x 2h): squarer tiles cut staging ~35%.
// ema tile [19][9][24] (was [19][8][40]); xe tile [64][4][12] (was [64][4][21]);
// valid because even h0 rows share (h-6)>>2 and h>>2 (differ only when
// h0-6 = 3 mod 4 — impossible for even h0). Even/odd pixel-pair sharing of
// phases 1-3 preserved (pairs within one row; sims bit-identical in-pair).
__global__ __launch_bounds__(256) void pfst_main(
    const float* __restrict__ trg, const float* __restrict__ ema,
    const float* __restrict__ xe,  const float* __restrict__ mix,
    float* __restrict__ part)
{
    __shared__ float se[NC * 217];        // ema tile [19][9][24], stride 217 (pad)
    __shared__ float sx[NCF * 49];        // xe tile [64][4][12], stride 49 (pad)
    __shared__ float scn3[3 * 48];        // partial cell norms [3 chunks][48]
    __shared__ float red[4][3];

    int tid = threadIdx.x;
    int l = tid & 3;                      // lane in pixel quad
    int u = tid & 7;                      // lane in pair octet
    int lc = l & 1;                       // class-lane within pos/neg pair
    bool posH = (l < 2);                  // phase-4/5 role (per pixel)
    int q = tid >> 2;                     // pixel slot (0..63)
    int bid = blockIdx.x;
    int b = bid >> 8;
    int rem = bid & 255;
    int h0 = ((rem >> 2) << 1);           // even row base
    int w0 = (rem & 3) << 5;              // 0,32,64,96
    int h = h0 + (q >> 5);                // per-pixel row
    int w = w0 + (q & 31);                // per-pixel col

    int eyB = (h0 - 7) >> 1, exB = (w0 - 7) >> 1;  // ema tile origin
    int by0 = (h0 - 6) >> 2, bx0 = (w0 - 6) >> 2;  // cell tile origin (row-shared)

    // ---------- Stage: xe->regs first, then ema->regs (issue order!) ----------
    float xreg[12];
    {
        const float* Xb = xe + b * (NCF * NHX * NHX);
        #pragma unroll
        for (int r = 0; r < 12; r++) {
            int idx = tid + r * 256;      // < 3072 exactly
            int ch = idx / 48; int rr = idx - ch * 48;
            int a = rr / 12;   int d = rr - a * 12;
            int gy = clampi(by0 + a, 0, 31), gx = clampi(bx0 + d, 0, 31);
            xreg[r] = Xb[ch * (NHX * NHX) + gy * 32 + gx];
        }
    }
    float ereg[17];
    {
        const float* Eb = ema + b * NC * (NHE * NHE);
        #pragma unroll
        for (int r = 0; r < 17; r++) {
            int idx = tid + r * 256;      // < 4352; valid < 4104
            if (idx < NC * 216) {
                int c = idx / 216; int rr = idx - c * 216;
                int rw = rr / 24;  int x = rr - rw * 24;
                int gy = clampi(eyB + rw, 0, 63), gx = clampi(exB + x, 0, 63);
                ereg[r] = Eb[c * (NHE * NHE) + gy * 64 + gx];
            } else ereg[r] = 0.f;
        }
    }
    // Write xe to LDS (waits only on xe loads; ema loads stay in flight)
    #pragma unroll
    for (int r = 0; r < 12; r++) {
        int idx = tid + r * 256;
        int ch = idx / 48; int rr = idx - ch * 48;
        sx[ch * 49 + rr] = xreg[r];
    }
    __syncthreads();

    // ---------- In-block cell norms: 3-chunk parallel split (48 cells) --------
    if (tid < 144) {
        int cell = tid % 48;
        int chunk = tid / 48;
        int ch0 = chunk * 21;
        int nch = (chunk == 2) ? 22 : 21;
        float s = 0.f;
        #pragma unroll
        for (int cc = 0; cc < 22; cc++) {
            if (cc < nch) {
                float v = sx[(ch0 + cc) * 49 + cell];
                s = fmaf(v, v, s);
            }
        }
        scn3[chunk * 48 + cell] = s;
    }
    __syncthreads();

    float mval = mix[(b << 14) + (h << 7) + w];
    bool active = mval < 0.5f;            // (1 - mix) > 0.5
    float af = active ? 1.f : 0.f;
    af += __shfl_xor(af, 4);
    bool apair = (af > 0.f);

    float lp = 0.f, ln = 0.f;
    float cm = (active && l == 0) ? 1.f : 0.f;

    float tx[10];
    float vsel[9]; int isel[9];

    if (active) {
        // ---------- Prefetch trg for this lane's 10 classes ----------
        const float* Tb = trg + b * NC * (NH * NW) + (h << 7) + w;
        #pragma unroll
        for (int jc = 0; jc < 10; jc++) {
            int c = lc + 2 * jc;
            tx[jc] = (c < NC) ? Tb[c * (NH * NW)] : 0.f;
        }
    }

    if (apair) {
        // ---------- Phase 1: cell dots, 8 channels/lane across the pair -------
        int bx = (w - 6) >> 2;
        int trow[4], tcol[4];
        #pragma unroll
        for (int a = 0; a < 4; a++) trow[a] = clampi(by0 + a, 0, 31) - by0;
        #pragma unroll
        for (int d = 0; d < 4; d++) tcol[d] = clampi(bx + d, 0, 31) - bx0;
        int coffT = ((h >> 2) - by0) * 12 + ((w >> 2) - bx0);   // pair-identical

        float dotc[16];
        #pragma unroll
        for (int e = 0; e < 16; e++) dotc[e] = 0.f;

        #pragma unroll
        for (int cc = 0; cc < 8; cc++) {
            const float* Sx = sx + (u * 8 + cc) * 49;
            float cv = Sx[coffT];
            #pragma unroll
            for (int a = 0; a < 4; a++) {
                int rb = trow[a] * 12;
                #pragma unroll
                for (int d = 0; d < 4; d++)
                    dotc[a * 4 + d] = fmaf(Sx[rb + tcol[d]], cv, dotc[a * 4 + d]);
            }
        }
        #pragma unroll
        for (int e = 0; e < 16; e++) {
            dotc[e] += __shfl_xor(dotc[e], 1);
            dotc[e] += __shfl_xor(dotc[e], 2);
            dotc[e] += __shfl_xor(dotc[e], 4);
        }

        float cn_c = (scn3[coffT] + scn3[48 + coffT]) + scn3[96 + coffT];
        float nc2 = 1.f / fmaxf(sqrtf(cn_c), EPSC);
        float scell[16];
        #pragma unroll
        for (int a = 0; a < 4; a++) {
            #pragma unroll
            for (int d = 0; d < 4; d++) {
                int x = trow[a] * 12 + tcol[d];
                float cn_u = (scn3[x] + scn3[48 + x]) + scn3[96 + x];
                float nu = fmaxf(sqrtf(cn_u), EPSC);
                scell[a * 4 + d] = dotc[a * 4 + d] * nc2 / nu;
            }
        }

        // ---------- Phase 2: 49 sims (pair-identical); lanes 4-7 NEGATED ------
        const int QA[7] = {0, 0, 1, 1, 2, 2, 3};
        const int QB[7] = {0, 1, 1, 2, 2, 3, 3};
        bool ry = (h & 3) >= 2, rx = (w & 3) >= 2;
        bool posScan = (u < 4);

        float sims[49];
        #pragma unroll
        for (int i = 0; i < 7; i++) {
            int py = h + 2 * i - 6;
            bool vy = (unsigned)py < 128u;
            float srow[4];
            #pragma unroll
            for (int d = 0; d < 4; d++)
                srow[d] = ry ? scell[QA[i] * 4 + d] : scell[QB[i] * 4 + d];
            #pragma unroll
            for (int j = 0; j < 7; j++) {
                int px = w + 2 * j - 6;
                bool vx = (unsigned)px < 128u;
                float v = rx ? srow[QA[j]] : srow[QB[j]];
                float sv = (vy && vx) ? v : 0.f;
                sims[i * 7 + j] = posScan ? sv : -sv;
            }
        }

        // ---------- Phase 3: 4-way-split 9-round scan per half ----------
        int s4 = u & 3;
        float hv[13];
        #pragma unroll
        for (int kk = 0; kk < 13; kk++) {
            float v0 = (kk < 12) ? sims[kk]      : -3.4e38f;
            float v1 = (kk < 12) ? sims[12 + kk] : -3.4e38f;
            float v2 = (kk < 12) ? sims[24 + kk] : -3.4e38f;
            float v3 = sims[36 + kk];
            float lo = (s4 & 1) ? v1 : v0;
            float hi = (s4 & 1) ? v3 : v2;
            hv[kk] = (s4 & 2) ? hi : lo;
        }
        int k0 = s4 * 12;
        int nown = (s4 == 3) ? 13 : 12;
        {
            unsigned mymask = 0u;
            #pragma unroll
            for (int t = 0; t < 9; t++) {
                float best = -3.4e38f; int bkk = 20;
                #pragma unroll
                for (int kk = 0; kk < 13; kk++) {
                    if (!((mymask >> kk) & 1u) && hv[kk] > best) { best = hv[kk]; bkk = kk; }
                }
                int bi = k0 + bkk;
                #pragma unroll
                for (int st = 1; st <= 2; st <<= 1) {
                    float ov = __shfl_xor(best, st);
                    int   oi = __shfl_xor(bi, st);
                    if (ov > best || (ov == best && oi < bi)) { best = ov; bi = oi; }
                }
                vsel[t] = best; isel[t] = bi;
                int rel = bi - k0;
                if ((unsigned)rel < (unsigned)nown) mymask |= 1u << rel;
            }
        }

        // ---------- Exchange across the pair: match pos/neg role ----------
        bool useOwn = ((u < 4) == (l < 2));
        #pragma unroll
        for (int t = 0; t < 9; t++) {
            float ov = __shfl_xor(vsel[t], 4);
            int   oi = __shfl_xor(isel[t], 4);
            vsel[t] = useOwn ? vsel[t] : ov;
            isel[t] = useOwn ? isel[t] : oi;
        }
    }

    // ---------- Deferred ema tile write (loads have long completed) ----------
    #pragma unroll
    for (int r = 0; r < 17; r++) {
        int idx = tid + r * 256;
        if (idx < NC * 216) {
            int c = idx / 216; int rr = idx - c * 216;
            se[c * 217 + rr] = ereg[r];
        }
    }
    __syncthreads();

    if (active) {
        // ---------- Phase 4: gather from LDS ema tile, 10 classes/lane --------
        float av[10];
        #pragma unroll
        for (int jc = 0; jc < 10; jc++) av[jc] = 0.f;

        #pragma unroll
        for (int t = 0; t < 9; t++) {
            if (posH || t < 8) {
                int k = isel[t];
                float val = posH ? vsel[t] : -vsel[t];
                int i = (k * 586) >> 12; int j = k - 7 * i;
                int py = h + 2 * i - 6, px = w + 2 * j - 6;
                if ((unsigned)py < 128u && (unsigned)px < 128u) {
                    int iy0 = (py - 1) >> 1; float ty = (py & 1) ? 0.25f : 0.75f;
                    int ix0 = (px - 1) >> 1; float txx = (px & 1) ? 0.25f : 0.75f;
                    int y0 = clampi(iy0, 0, 63), y1 = clampi(iy0 + 1, 0, 63);
                    int x0 = clampi(ix0, 0, 63), x1 = clampi(ix0 + 1, 0, 63);
                    float w00 = (1.f - ty) * (1.f - txx), w01 = (1.f - ty) * txx;
                    float w10 = ty * (1.f - txx),         w11 = ty * txx;
                    int o00 = (y0 - eyB) * 24 + (x0 - exB), o01 = (y0 - eyB) * 24 + (x1 - exB);
                    int o10 = (y1 - eyB) * 24 + (x0 - exB), o11 = (y1 - eyB) * 24 + (x1 - exB);
                    #pragma unroll
                    for (int jc = 0; jc < 10; jc++) {
                        int c = lc + 2 * jc;
                        if (c < NC) {
                            const float* Sc = se + c * 217;
                            float g = w00 * Sc[o00] + w01 * Sc[o01]
                                    + w10 * Sc[o10] + w11 * Sc[o11];
                            av[jc] = fmaf(val, g, av[jc]);
                        }
                    }
                }
            }
        }

        // ---------- Phase 5: softmax + BCE within each pos/neg pair ----------
        float m = -3.4e38f;
        #pragma unroll
        for (int jc = 0; jc < 10; jc++) {
            int c = lc + 2 * jc;
            if (c < NC) m = fmaxf(m, av[jc]);
        }
        m = fmaxf(m, __shfl_xor(m, 1));

        float Z = 0.f, S = 0.f, Bs = 0.f;
        #pragma unroll
        for (int jc = 0; jc < 10; jc++) {
            int c = lc + 2 * jc;
            if (c < NC) {
                float x = tx[jc];
                float e = expf(av[jc] - m); Z += e; S += e * x;
                float ls = fminf(x, 0.f) - log1pf(expf(-fabsf(x)));  // log_sigmoid
                Bs += x - ls;
            }
        }
        Z += __shfl_xor(Z, 1); S += __shfl_xor(S, 1); Bs += __shfl_xor(Bs, 1);

        float res = posH ? (Bs - S / Z) : (S / Z - Bs);
        float oth = __shfl_xor(res, 2);       // lane 0 <- lane 2's neg result
        lp = (l == 0) ? res : 0.f;            // sum_c bce(x, pl_pos)
        ln = (l == 0) ? oth : 0.f;            // sum_c -bce(x, pl_neg)
    }

    // ---------- Wave reduce, block reduce, per-block partial store ----------
    #pragma unroll
    for (int off = 32; off > 0; off >>= 1) {
        lp += __shfl_down(lp, off);
        ln += __shfl_down(ln, off);
        cm += __shfl_down(cm, off);
    }
    int wid = tid >> 6;
    if ((tid & 63) == 0) { red[wid][0] = lp; red[wid][1] = ln; red[wid][2] = cm; }
    __syncthreads();
    if (tid == 0) {
        float* pb = part + 3 * blockIdx.x;
        pb[0] = red[0][0] + red[1][0] + red[2][0] + red[3][0];
        pb[1] = red[0][1] + red[1][1] + red[2][1] + red[3][1];
        pb[2] = red[0][2] + red[1][2] + red[2][2] + red[3][2];
    }
}

// Final reduction of NBLK per-block partials (no atomics anywhere).
// Output: FLOAT32[2] = [loss_pos, 0.1*loss_neg] (decoded R0-R10, verified R11+).
__global__ __launch_bounds__(256) void pfst_final(const float* __restrict__ part,
                                                  float* __restrict__ out) {
    int t = threadIdx.x;
    float lp = part[3 * t + 0] + part[3 * (t + 256) + 0];
    float ln = part[3 * t + 1] + part[3 * (t + 256) + 1];
    float cm = part[3 * t + 2] + part[3 * (t + 256) + 2];
    #pragma unroll
    for (int off = 32; off > 0; off >>= 1) {
        lp += __shfl_down(lp, off);
        ln += __shfl_down(ln, off);
        cm += __shfl_down(cm, off);
    }
    __shared__ float red[4][3];
    int wid = t >> 6;
    if ((t & 63) == 0) { red[wid][0] = lp; red[wid][1] = ln; red[wid][2] = cm; }
    __syncthreads();
    if (t == 0) {
        float a0 = red[0][0] + red[1][0] + red[2][0] + red[3][0];
        float a1 = red[0][1] + red[1][1] + red[2][1] + red[3][1];
        float a2 = red[0][2] + red[1][2] + red[2][2] + red[3][2];
        float denom = a2 * (float)NC;
        out[0] = a0 / denom;              // loss_pos * W_POS(=1.0)
        out[1] = a1 / denom * 0.1f;       // loss_neg * W_NEG(=0.1)
    }
}

extern "C" void kernel_launch(void* const* d_in, const int* in_sizes, int n_in,
                              void* d_out, int out_size, void* d_ws, size_t ws_size,
                              hipStream_t stream) {
    const float* trg = (const float*)d_in[0];   // [2,19,128,128]
    const float* ema = (const float*)d_in[1];   // [2,19,64,64]
    const float* xe  = (const float*)d_in[2];   // [2,64,32,32]
    const float* mix = (const float*)d_in[3];   // [2,1,128,128]
    float* part = (float*)((char*)d_ws + WS_PART_OFF);
    float* out  = (float*)d_out;

    hipLaunchKernelGGL(pfst_main, dim3(NBLK), dim3(256), 0, stream,
                       trg, ema, xe, mix, part);
    hipLaunchKernelGGL(pfst_final, dim3(1), dim3(256), 0, stream, part, out);
}